// Round 6
// baseline (192.572 us; speedup 1.0000x reference)
//
#include <hip/hip_runtime.h>
#include <hip/hip_bf16.h>

// LinearAttention_MLP on MI355X — round 11: fused main, B direct global->reg.
// Math: k-softmax over size-1 axis == 1 -> s = 0.125 exactly -> out = 0.125*v.
// Fold: y = x @ Weff^T, Weff = 0.125*Wo@Wv (1024x1024).
// Pipeline (2 launches):
//   weff_only  : Weff = bf16(0.125*Wo@Wv), 256 blocks (validated round-5 body)
//   main_fused : block = 64 rows x 1024 cols, 256 blocks (1/CU), 512 thr
//                (8 waves, wave = 128-col slice). BK=32, 32 K-tiles.
//                B: wave-private slice -> DIRECT global->VGPR frags (bf16x8),
//                   double-buffered in regs (b0/b1), no LDS, no barrier, no
//                   hand vmcnt (compiler's counted waits; ~1 tile in flight).
//                   Rationale: zero intra-block B reuse (each LDS byte was
//                   read once) + Weff L2-resident => LDS staging was overhead.
//                A: 4KB/tile LDS dbuf, threads 0..255 produce. Conflict-free
//                   slot map (enumerated): slot t = row*4 + (kq^((row>>1)&3)),
//                   row = t>>2; frag-read octets cover all 8 bank-quads.
//                ONE s_barrier per tile (A visibility), zero vmcnt drains.
//                Epilogue: bias -> per-row sumsq (shfl-xor + LDS) ->
//                sc = 32/max(||y||,eps) -> out fp32 from registers.
//                (validated numerics, round 10)
//
// WORKSPACE: 2 MB (Weff) only.

typedef __attribute__((ext_vector_type(8))) short bf16x8;
typedef __attribute__((ext_vector_type(4))) float f32x4;

struct alignas(16) bfvec8 { __hip_bfloat16 h[8]; };

__device__ __forceinline__ bfvec8 pack8(float4 a, float4 b) {
    bfvec8 o;
    o.h[0] = __float2bfloat16(a.x); o.h[1] = __float2bfloat16(a.y);
    o.h[2] = __float2bfloat16(a.z); o.h[3] = __float2bfloat16(a.w);
    o.h[4] = __float2bfloat16(b.x); o.h[5] = __float2bfloat16(b.y);
    o.h[6] = __float2bfloat16(b.z); o.h[7] = __float2bfloat16(b.w);
    return o;
}

// ---------------- weff_only: Weff = 0.125 * Wo @ Wv, fp32 in, bf16 out ----------------
__global__ __launch_bounds__(256)
void weff_only(const float* __restrict__ Wo, const float* __restrict__ Wv,
               __hip_bfloat16* __restrict__ Weff) {
    __shared__ __align__(16) __hip_bfloat16 As[64 * 32];
    __shared__ __align__(16) __hip_bfloat16 Bs[64 * 32];
    __shared__ __align__(16) float Bf[32 * 65];

    const int tid  = threadIdx.x;
    const int lane = tid & 63;
    const int wave = tid >> 6;
    const int wm   = wave >> 1;
    const int wn   = wave & 1;
    const int quad = lane >> 4;
    const int tr   = lane & 15;
    const int m0   = (blockIdx.x >> 4) * 64;
    const int n0   = (blockIdx.x & 15) * 64;

    f32x4 acc[2][2];
#pragma unroll
    for (int i = 0; i < 2; ++i)
#pragma unroll
        for (int j = 0; j < 2; ++j)
            acc[i][j] = (f32x4){0.f, 0.f, 0.f, 0.f};

    for (int kt = 0; kt < 512; kt += 32) {
        {
            int r = tid >> 2, c = tid & 3;
            int s = (r >> 1) & 3;
            int kg = (c ^ s) << 3;
            const float* sp = Wo + (size_t)(m0 + r) * 512 + kt + kg;
            float4 a = *(const float4*)sp, b = *(const float4*)(sp + 4);
            *(bfvec8*)(As + r * 32 + (c << 3)) = pack8(a, b);
        }
        {
            int kr = tid >> 3, c8 = (tid & 7) << 3;
            const float* sp = Wv + (size_t)(kt + kr) * 1024 + n0 + c8;
            float4 a = *(const float4*)sp, b = *(const float4*)(sp + 4);
            *(float4*)(Bf + kr * 65 + c8)     = a;
            *(float4*)(Bf + kr * 65 + c8 + 4) = b;
        }
        __syncthreads();
        {
            int n = tid >> 2, cc = tid & 3, k8 = cc << 3;
            float4 a, b;
            a.x = Bf[(k8 + 0) * 65 + n]; a.y = Bf[(k8 + 1) * 65 + n];
            a.z = Bf[(k8 + 2) * 65 + n]; a.w = Bf[(k8 + 3) * 65 + n];
            b.x = Bf[(k8 + 4) * 65 + n]; b.y = Bf[(k8 + 5) * 65 + n];
            b.z = Bf[(k8 + 6) * 65 + n]; b.w = Bf[(k8 + 7) * 65 + n];
            int cs = cc ^ ((n >> 1) & 3);
            *(bfvec8*)(Bs + n * 32 + cs * 8) = pack8(a, b);
        }
        __syncthreads();

        bf16x8 af[2], bfr[2];
#pragma unroll
        for (int mi = 0; mi < 2; ++mi) {
            int r = wm * 32 + mi * 16 + tr;
            int c = quad ^ ((r >> 1) & 3);
            af[mi] = *(const bf16x8*)(As + r * 32 + c * 8);
        }
#pragma unroll
        for (int ni = 0; ni < 2; ++ni) {
            int r = wn * 32 + ni * 16 + tr;
            int c = quad ^ ((r >> 1) & 3);
            bfr[ni] = *(const bf16x8*)(Bs + r * 32 + c * 8);
        }
#pragma unroll
        for (int mi = 0; mi < 2; ++mi)
#pragma unroll
            for (int ni = 0; ni < 2; ++ni)
                acc[mi][ni] = __builtin_amdgcn_mfma_f32_16x16x32_bf16(
                    af[mi], bfr[ni], acc[mi][ni], 0, 0, 0);
        __syncthreads();
    }

#pragma unroll
    for (int mi = 0; mi < 2; ++mi)
#pragma unroll
        for (int ni = 0; ni < 2; ++ni) {
            const int col = n0 + wn * 32 + ni * 16 + tr;
#pragma unroll
            for (int r = 0; r < 4; ++r) {
                const int row = m0 + wm * 32 + mi * 16 + quad * 4 + r;
                Weff[(size_t)row * 1024 + col] =
                    __float2bfloat16(acc[mi][ni][r] * 0.125f);
            }
        }
}

// ---------------- main_fused: y = X @ Weff^T + b, RMSNorm fused, fp32 out ----------------
__global__ __launch_bounds__(512, 1)
void main_fused(const float* __restrict__ X,
                const __hip_bfloat16* __restrict__ W,
                const float* __restrict__ bias,
                const float* __restrict__ g,
                float* __restrict__ out) {
    __shared__ __align__(16) __hip_bfloat16 Asm[2][2048];   // 2 x 4 KiB
    __shared__ float wpart[8][64];
    __shared__ float scrow[64];

    const int tid  = threadIdx.x;          // 0..511
    const int lane = tid & 63;
    const int wc   = tid >> 6;             // wave = col group (128 cols)
    const int quad = lane >> 4;
    const int tr   = lane & 15;
    const int m0   = blockIdx.x * 64;

    // A producers (threads 0..255): slot t holds global (row = t>>2,
    // kchunk = (t&3) ^ ((t>>3)&3)). Linear b128 write at elem t*8.
    const int arow = tid >> 2;
    const int akq  = (tid & 3) ^ ((tid >> 3) & 3);
    const float* Agp = X + (size_t)(m0 + arow) * 1024 + akq * 8;

    // A frag reads: global (row = mi*16+tr, kchunk = quad) lives at
    // slot = row*4 + (quad ^ ((row>>1)&3)). Octets cover all 8 bank-quads.
    int aoff[4];
#pragma unroll
    for (int mi = 0; mi < 4; ++mi) {
        const int row = mi * 16 + tr;
        aoff[mi] = (row * 4 + (quad ^ ((row >> 1) & 3))) * 8;   // elems
    }

    // B direct-load lane base: row wc*128 + tr, k bytes quad*16.
    // Frag (ni, tile u): Wb + ni*16*1024 + u*32 (elems).
    const __hip_bfloat16* Wb = W + (size_t)(wc * 128 + tr) * 1024 + quad * 8;

    f32x4 acc[4][8];
#pragma unroll
    for (int mi = 0; mi < 4; ++mi)
#pragma unroll
        for (int ni = 0; ni < 8; ++ni)
            acc[mi][ni] = (f32x4){0.f, 0.f, 0.f, 0.f};

    float4 pa0, pa1;
    bf16x8 b0[8], b1[8], af[4];

    // ---- Prologue: A(0) -> Asm[0]; B(0) -> b0 ----
    if (tid < 256) {
        pa0 = *(const float4*)Agp;
        pa1 = *(const float4*)(Agp + 4);
    }
#pragma unroll
    for (int ni = 0; ni < 8; ++ni)
        b0[ni] = *(const bf16x8*)(Wb + ni * 16384);
    if (tid < 256)
        *(bfvec8*)(&Asm[0][tid * 8]) = pack8(pa0, pa1);
    __syncthreads();

    // ---- Main loop: 32 K-tiles, one barrier per tile, no vmcnt drains ----
#define BODY(U, P, BC, BN) do { \
    const int u_ = (U); \
    if (u_ < 31) { \
        if (tid < 256) { \
            pa0 = *(const float4*)(Agp + (u_ + 1) * 32); \
            pa1 = *(const float4*)(Agp + (u_ + 1) * 32 + 4); \
        } \
        _Pragma("unroll") \
        for (int ni = 0; ni < 8; ++ni) \
            BN[ni] = *(const bf16x8*)(Wb + ni * 16384 + (u_ + 1) * 32); \
    } \
    _Pragma("unroll") \
    for (int mi = 0; mi < 4; ++mi) \
        af[mi] = *(const bf16x8*)(&Asm[P][aoff[mi]]); \
    __builtin_amdgcn_s_setprio(1); \
    _Pragma("unroll") \
    for (int mi = 0; mi < 4; ++mi) \
        _Pragma("unroll") \
        for (int ni = 0; ni < 8; ++ni) \
            acc[mi][ni] = __builtin_amdgcn_mfma_f32_16x16x32_bf16( \
                af[mi], BC[ni], acc[mi][ni], 0, 0, 0); \
    __builtin_amdgcn_s_setprio(0); \
    if (u_ < 31) { \
        if (tid < 256) \
            *(bfvec8*)(&Asm[(P) ^ 1][tid * 8]) = pack8(pa0, pa1); \
        asm volatile("s_waitcnt lgkmcnt(0)" ::: "memory"); \
        __builtin_amdgcn_s_barrier(); \
        __builtin_amdgcn_sched_barrier(0); \
    } \
} while (0)

    for (int it = 0; it < 16; ++it) {
        BODY(it * 2,     0, b0, b1);
        BODY(it * 2 + 1, 1, b1, b0);
    }
#undef BODY

    // ---- Fused epilogue: bias -> per-row ||y||^2 -> sc -> fp32 out ----
    float bvv[8], gvv[8];
    int coln[8];
#pragma unroll
    for (int ni = 0; ni < 8; ++ni) {
        coln[ni] = wc * 128 + ni * 16 + tr;
        bvv[ni] = bias[coln[ni]];
        gvv[ni] = g[coln[ni]];
    }

#pragma unroll
    for (int mi = 0; mi < 4; ++mi)
#pragma unroll
        for (int rr = 0; rr < 4; ++rr) {
            float p = 0.f;
#pragma unroll
            for (int ni = 0; ni < 8; ++ni) {
                const float t = acc[mi][ni][rr] + bvv[ni];
                acc[mi][ni][rr] = t;
                p += t * t;
            }
            // reduce over the 16 tr-lanes (same output row, this wave's 128 cols)
#pragma unroll
            for (int msk = 1; msk < 16; msk <<= 1)
                p += __shfl_xor(p, msk, 64);
            if (tr == 0) wpart[wc][mi * 16 + quad * 4 + rr] = p;
        }
    __syncthreads();

    if (tid < 64) {
        float s = 0.f;
#pragma unroll
        for (int w = 0; w < 8; ++w) s += wpart[w][tid];
        scrow[tid] = 32.0f / fmaxf(sqrtf(s), 1e-12f);
    }
    __syncthreads();

#pragma unroll
    for (int mi = 0; mi < 4; ++mi)
#pragma unroll
        for (int rr = 0; rr < 4; ++rr) {
            const int r16 = mi * 16 + quad * 4 + rr;
            const float sc = scrow[r16];
#pragma unroll
            for (int ni = 0; ni < 8; ++ni)
                out[(size_t)(m0 + r16) * 1024 + coln[ni]] =
                    acc[mi][ni][rr] * sc * gvv[ni];
        }
}

extern "C" void kernel_launch(void* const* d_in, const int* in_sizes, int n_in,
                              void* d_out, int out_size, void* d_ws, size_t ws_size,
                              hipStream_t stream) {
    const float* x     = (const float*)d_in[0];   // (16384, 1024)
    const float* w_qkv = (const float*)d_in[1];   // (1536, 1024)
    const float* w_out = (const float*)d_in[2];   // (1024, 512)
    const float* b_out = (const float*)d_in[3];   // (1024,)
    const float* g     = (const float*)d_in[4];   // (1, 1024)

    const int D = 1024, H = 512;
    const float* wv = w_qkv + (size_t)2 * H * D;  // v-rows: (512, 1024)

    __hip_bfloat16* weff_bf = (__hip_bfloat16*)d_ws;   // 2 MB

    weff_only<<<256, 256, 0, stream>>>(w_out, wv, weff_bf);
    main_fused<<<256, 512, 0, stream>>>(x, weff_bf, b_out, g, (float*)d_out);
}

// Round 7
// 177.233 us; speedup vs baseline: 1.0865x; 1.0865x over previous
//
#include <hip/hip_runtime.h>
#include <hip/hip_bf16.h>

// LinearAttention_MLP on MI355X — round 12: round-7 pipeline, 2-phase K-tiles.
// Math: k-softmax over size-1 axis == 1 -> s = 0.125 exactly -> out = 0.125*v.
// Fold: y = x @ Weff^T, Weff = 0.125*Wo@Wv (1024x1024).
// Pipeline (3 launches, = round 7 except main_gemm's phase structure):
//   prep       : [0..255] Weff = bf16(0.125*Wo@Wv); [256..2303] Xbf = bf16(X)
//   main_gemm  : y_bf = bf16(Xbf@Weff^T + b). 256x256, BK=64, 512 thr, dbuf
//                128KB. TWO phases per K-tile (was 4), each = 128-row A-half
//                split into two barrier-free MFMA sub-batches; batch-2 ds_reads
//                are compiler-scheduled to overlap batch-1 MFMA. Barrier+drain
//                pairs per K-tile: 8 -> 4.
//                Staging (ledger-verified): P0: A1(u+1)->rb^1 (2 gll);
//                P1: B0,B1,A0(u+2)->rb (6 gll); boundary vmcnt(6) completes
//                tile u+1 exactly, keeps tile u+2's 6 loads in flight.
//                Races: B read only at P0; A0 rows read only at P0; all reads
//                drained pre-MFMA before the barrier that precedes the gll.
//   rmsnorm2   : out = y/max(||y||,eps)*g*32  (fp32, unchanged)
//
// Swizzle convention (validated, 0 bank conflicts):
//   STORE: LDS chunk c holds GLOBAL chunk c ^ (r&7)  (swizzle the global k only)
//   READ : global chunk q lives in LDS chunk q ^ (r&7)
//
// WORKSPACE: 2MB (Weff) + 33.6MB (y_bf) + 33.6MB (Xbf) = ~69.2 MB.

typedef __attribute__((ext_vector_type(8))) short bf16x8;
typedef __attribute__((ext_vector_type(4))) float f32x4;

struct alignas(16) bfvec8 { __hip_bfloat16 h[8]; };

__device__ __forceinline__ bfvec8 pack8(float4 a, float4 b) {
    bfvec8 o;
    o.h[0] = __float2bfloat16(a.x); o.h[1] = __float2bfloat16(a.y);
    o.h[2] = __float2bfloat16(a.z); o.h[3] = __float2bfloat16(a.w);
    o.h[4] = __float2bfloat16(b.x); o.h[5] = __float2bfloat16(b.y);
    o.h[6] = __float2bfloat16(b.z); o.h[7] = __float2bfloat16(b.w);
    return o;
}

// ---------------- prep: weff (blocks 0..255) + X->bf16 cvt (blocks 256..2303) ----------
__global__ __launch_bounds__(256)
void prep(const float* __restrict__ Wo, const float* __restrict__ Wv,
          __hip_bfloat16* __restrict__ Weff,
          const float* __restrict__ X, __hip_bfloat16* __restrict__ Xbf) {
    __shared__ __align__(16) __hip_bfloat16 As[64 * 32];
    __shared__ __align__(16) __hip_bfloat16 Bs[64 * 32];
    __shared__ __align__(16) float Bf[32 * 65];

    const int tid = threadIdx.x;

    if (blockIdx.x >= 256) {
        const size_t nv = (size_t)16384 * 1024 / 8;          // 2,097,152 vec8
        const size_t stride = (size_t)2048 * 256;
        for (size_t i = (size_t)(blockIdx.x - 256) * 256 + tid; i < nv; i += stride) {
            const float4 a = *(const float4*)(X + i * 8);
            const float4 b = *(const float4*)(X + i * 8 + 4);
            *(bfvec8*)(Xbf + i * 8) = pack8(a, b);
        }
        return;
    }

    // ---- weff body (validated): Weff = 0.125 * Wo @ Wv ----
    const int lane = tid & 63;
    const int wave = tid >> 6;
    const int wm   = wave >> 1;
    const int wn   = wave & 1;
    const int quad = lane >> 4;
    const int tr   = lane & 15;
    const int m0   = (blockIdx.x >> 4) * 64;
    const int n0   = (blockIdx.x & 15) * 64;

    f32x4 acc[2][2];
#pragma unroll
    for (int i = 0; i < 2; ++i)
#pragma unroll
        for (int j = 0; j < 2; ++j)
            acc[i][j] = (f32x4){0.f, 0.f, 0.f, 0.f};

    for (int kt = 0; kt < 512; kt += 32) {
        {
            int r = tid >> 2, c = tid & 3;
            int s = (r >> 1) & 3;
            int kg = (c ^ s) << 3;
            const float* sp = Wo + (size_t)(m0 + r) * 512 + kt + kg;
            float4 a = *(const float4*)sp, b = *(const float4*)(sp + 4);
            *(bfvec8*)(As + r * 32 + (c << 3)) = pack8(a, b);
        }
        {
            int kr = tid >> 3, c8 = (tid & 7) << 3;
            const float* sp = Wv + (size_t)(kt + kr) * 1024 + n0 + c8;
            float4 a = *(const float4*)sp, b = *(const float4*)(sp + 4);
            *(float4*)(Bf + kr * 65 + c8)     = a;
            *(float4*)(Bf + kr * 65 + c8 + 4) = b;
        }
        __syncthreads();
        {
            int n = tid >> 2, cc = tid & 3, k8 = cc << 3;
            float4 a, b;
            a.x = Bf[(k8 + 0) * 65 + n]; a.y = Bf[(k8 + 1) * 65 + n];
            a.z = Bf[(k8 + 2) * 65 + n]; a.w = Bf[(k8 + 3) * 65 + n];
            b.x = Bf[(k8 + 4) * 65 + n]; b.y = Bf[(k8 + 5) * 65 + n];
            b.z = Bf[(k8 + 6) * 65 + n]; b.w = Bf[(k8 + 7) * 65 + n];
            int cs = cc ^ ((n >> 1) & 3);
            *(bfvec8*)(Bs + n * 32 + cs * 8) = pack8(a, b);
        }
        __syncthreads();

        bf16x8 af[2], bfr[2];
#pragma unroll
        for (int mi = 0; mi < 2; ++mi) {
            int r = wm * 32 + mi * 16 + tr;
            int c = quad ^ ((r >> 1) & 3);
            af[mi] = *(const bf16x8*)(As + r * 32 + c * 8);
        }
#pragma unroll
        for (int ni = 0; ni < 2; ++ni) {
            int r = wn * 32 + ni * 16 + tr;
            int c = quad ^ ((r >> 1) & 3);
            bfr[ni] = *(const bf16x8*)(Bs + r * 32 + c * 8);
        }
#pragma unroll
        for (int mi = 0; mi < 2; ++mi)
#pragma unroll
            for (int ni = 0; ni < 2; ++ni)
                acc[mi][ni] = __builtin_amdgcn_mfma_f32_16x16x32_bf16(
                    af[mi], bfr[ni], acc[mi][ni], 0, 0, 0);
        __syncthreads();
    }

#pragma unroll
    for (int mi = 0; mi < 2; ++mi)
#pragma unroll
        for (int ni = 0; ni < 2; ++ni) {
            const int col = n0 + wn * 32 + ni * 16 + tr;
#pragma unroll
            for (int r = 0; r < 4; ++r) {
                const int row = m0 + wm * 32 + mi * 16 + quad * 4 + r;
                Weff[(size_t)row * 1024 + col] =
                    __float2bfloat16(acc[mi][ni][r] * 0.125f);
            }
        }
}

// ---------------- main GEMM: y = Xbf @ Weff^T + b, 256x256, 2-phase K-tiles ------------
// M=16384, N=1024, K=1024. Grid 256 blocks (64 m x 4 n), 512 threads (8 waves).
// LDS 128KB: buf b at b*32768 elems; A @ +0, B @ +16384; halves of 8192 elems.

#define GLL(gp, lp) __builtin_amdgcn_global_load_lds( \
    (const __attribute__((address_space(1))) void*)(gp), \
    (__attribute__((address_space(3))) void*)(lp), 16, 0, 0)

#define STAGE_A(BUF, H, U) do { \
    GLL(Xbf + Ab0 + (size_t)(H) * 131072 + (size_t)(U) * 64, \
        sm + (BUF) * 32768 + (H) * 8192 + ldsA);             \
    GLL(Xbf + Ab1 + (size_t)(H) * 131072 + (size_t)(U) * 64, \
        sm + (BUF) * 32768 + (H) * 8192 + 4096 + ldsA);      \
} while (0)

#define STAGE_B(BUF, H, U) do { \
    GLL(Bt + Bb0 + (size_t)(H) * 131072 + (size_t)(U) * 64,  \
        sm + (BUF) * 32768 + 16384 + (H) * 8192 + ldsA);     \
    GLL(Bt + Bb1 + (size_t)(H) * 131072 + (size_t)(U) * 64,  \
        sm + (BUF) * 32768 + 16384 + (H) * 8192 + 4096 + ldsA); \
} while (0)

__global__ __launch_bounds__(512, 2)
void main_gemm(const __hip_bfloat16* __restrict__ Xbf,
               const __hip_bfloat16* __restrict__ Bt,
               const float* __restrict__ bias,
               __hip_bfloat16* __restrict__ Y) {
    __shared__ __align__(16) __hip_bfloat16 sm[2 * 32768];   // 128 KiB

    const int tid  = threadIdx.x;          // 0..511
    const int lane = tid & 63;
    const int wc   = tid >> 6;             // wave = col group 0..7 (cols wc*32)
    const int quad = lane >> 4;
    const int tr   = lane & 15;
    const int rlow = tr & 7;

    // XCD-aware: 256 blocks; XCD x gets orig chunk [x*32, x*32+32) (8 m x 4 n)
    const int xcd  = blockIdx.x & 7;
    const int orig = xcd * 32 + (blockIdx.x >> 3);
    const int m0   = (orig >> 2) * 256;
    const int n0   = (orig & 3) * 256;

    // Staging constants (linear LDS dest, inverse-swizzled global k).
    const int r0 = tid >> 3,            c0 = tid & 7;
    const int r1 = (tid + 512) >> 3,    c1 = tid & 7;
    const size_t Ab0 = (size_t)(m0 + r0) * 1024 + ((c0 ^ (r0 & 7)) << 3);
    const size_t Ab1 = (size_t)(m0 + r1) * 1024 + ((c1 ^ (r1 & 7)) << 3);
    const size_t Bb0 = (size_t)(n0 + r0) * 1024 + ((c0 ^ (r0 & 7)) << 3);
    const size_t Bb1 = (size_t)(n0 + r1) * 1024 + ((c1 ^ (r1 & 7)) << 3);
    const int ldsA = tid * 8;

    // Read chunk offsets per ko: global chunk q = ko*4+quad lives in chunk q^rlow.
    int ac[2];
#pragma unroll
    for (int ko = 0; ko < 2; ++ko) ac[ko] = ((ko * 4 + quad) ^ rlow) * 8;
    const int rdA = tr * 64;                            // + q16*4096 + mi*1024
    const int rdB = wc * 2048 + tr * 64;                // + ni*1024

    f32x4 acc[16][2];
#pragma unroll
    for (int f = 0; f < 16; ++f)
#pragma unroll
        for (int ni = 0; ni < 2; ++ni)
            acc[f][ni] = (f32x4){0.f, 0.f, 0.f, 0.f};

    // ---- Prologue: stage [0.B0 0.B1 0.A0 0.A1 | 1.B0 1.B1 1.A0] = 14 loads ----
    STAGE_B(0, 0, 0); STAGE_B(0, 1, 0); STAGE_A(0, 0, 0); STAGE_A(0, 1, 0);
    STAGE_B(1, 0, 1); STAGE_B(1, 1, 1); STAGE_A(1, 0, 1);
    asm volatile("s_waitcnt vmcnt(6)" ::: "memory");     // tile 0 complete, 6 in flight
    __builtin_amdgcn_s_barrier();

    bf16x8 bfr[2][2];

    // ---- Main loop: 16 K-tiles x 2 phases; 4 barrier pairs/K-tile (was 8) ----
    for (int it = 0; it < 8; ++it) {
#pragma unroll
        for (int rb = 0; rb < 2; ++rb) {                 // rb = read buffer (static)
            const int u = it * 2 + rb;                   // K-tile index (uniform)
#pragma unroll
            for (int ph = 0; ph < 2; ++ph) {             // ph = 128-row A-half
                // batch-1 ds_reads: rows ph*128 .. ph*128+63 (sub-quarter ph*2)
                bf16x8 af[4][2];
#pragma unroll
                for (int mi = 0; mi < 4; ++mi)
#pragma unroll
                    for (int ko = 0; ko < 2; ++ko)
                        af[mi][ko] = *(const bf16x8*)(
                            sm + rb * 32768 + (ph * 2) * 4096 + mi * 1024 + rdA + ac[ko]);
                if (ph == 0) {                           // B frags for whole K-tile
#pragma unroll
                    for (int ni = 0; ni < 2; ++ni)
#pragma unroll
                        for (int ko = 0; ko < 2; ++ko)
                            bfr[ni][ko] = *(const bf16x8*)(
                                sm + rb * 32768 + 16384 + rdB + ni * 1024 + ac[ko]);
                }

                // staging (ledger in header comment)
                if (ph == 0) {
                    if (u + 1 < 16) STAGE_A(rb ^ 1, 1, u + 1);
                } else {
                    if (u + 2 < 16) {
                        STAGE_B(rb, 0, u + 2);
                        STAGE_B(rb, 1, u + 2);
                        STAGE_A(rb, 0, u + 2);
                    }
                }

                __builtin_amdgcn_s_barrier();
                asm volatile("s_waitcnt lgkmcnt(0)" ::: "memory");
                __builtin_amdgcn_sched_barrier(0);

                __builtin_amdgcn_s_setprio(1);
#pragma unroll
                for (int mi = 0; mi < 4; ++mi)
#pragma unroll
                    for (int ni = 0; ni < 2; ++ni)
#pragma unroll
                        for (int ko = 0; ko < 2; ++ko)
                            acc[ph * 8 + mi][ni] = __builtin_amdgcn_mfma_f32_16x16x32_bf16(
                                af[mi][ko], bfr[ni][ko], acc[ph * 8 + mi][ni], 0, 0, 0);
                __builtin_amdgcn_s_setprio(0);

                // batch-2 ds_reads (rows ph*128+64 ..): compiler overlaps with
                // batch-1 MFMA and inserts the precise lgkm wait before use.
                bf16x8 ag[4][2];
#pragma unroll
                for (int mi = 0; mi < 4; ++mi)
#pragma unroll
                    for (int ko = 0; ko < 2; ++ko)
                        ag[mi][ko] = *(const bf16x8*)(
                            sm + rb * 32768 + (ph * 2 + 1) * 4096 + mi * 1024 + rdA + ac[ko]);

                __builtin_amdgcn_s_setprio(1);
#pragma unroll
                for (int mi = 0; mi < 4; ++mi)
#pragma unroll
                    for (int ni = 0; ni < 2; ++ni)
#pragma unroll
                        for (int ko = 0; ko < 2; ++ko)
                            acc[ph * 8 + 4 + mi][ni] = __builtin_amdgcn_mfma_f32_16x16x32_bf16(
                                ag[mi][ko], bfr[ni][ko], acc[ph * 8 + 4 + mi][ni], 0, 0, 0);
                __builtin_amdgcn_s_setprio(0);

                if (ph == 1) {
                    // boundary: counted drain completes exactly tile u+1
                    if (u <= 13)      asm volatile("s_waitcnt vmcnt(6)" ::: "memory");
                    else if (u == 14) asm volatile("s_waitcnt vmcnt(0)" ::: "memory");
                    if (u < 15) __builtin_amdgcn_s_barrier();
                } else {
                    __builtin_amdgcn_s_barrier();
                }
            }
        }
    }

    // ---- Epilogue: C/D layout col = lane&15 (tr), row = quad*4 + reg ----
    float bv[2]; int col[2];
#pragma unroll
    for (int ni = 0; ni < 2; ++ni) {
        col[ni] = n0 + wc * 32 + ni * 16 + tr;
        bv[ni]  = bias[col[ni]];
    }
#pragma unroll
    for (int f = 0; f < 16; ++f)
#pragma unroll
        for (int ni = 0; ni < 2; ++ni)
#pragma unroll
            for (int rr = 0; rr < 4; ++rr) {
                const int row = m0 + f * 16 + quad * 4 + rr;
                Y[(size_t)row * 1024 + col[ni]] =
                    __float2bfloat16(acc[f][ni][rr] + bv[ni]);
            }
}

// ---------------- norm: out = y / max(||y||,eps) * g * 32, 2 rows/block ----------------
__global__ __launch_bounds__(256)
void rmsnorm2(const __hip_bfloat16* __restrict__ y, const float* __restrict__ g,
              float* __restrict__ out) {
    const int wave = threadIdx.x >> 6;
    const int sub  = wave >> 1;
    const int t    = threadIdx.x & 127;
    const int row  = blockIdx.x * 2 + sub;
    const size_t base = (size_t)row * 1024 + t * 8;

    union { uint4 u; ushort s[8]; } U;
    U.u = *(const uint4*)(y + base);
    float v[8];
#pragma unroll
    for (int j = 0; j < 8; ++j)
        v[j] = __bfloat162float(*(const __hip_bfloat16*)&U.s[j]);

    float ss = 0.f;
#pragma unroll
    for (int j = 0; j < 8; ++j) ss += v[j] * v[j];
#pragma unroll
    for (int off = 32; off > 0; off >>= 1)
        ss += __shfl_down(ss, off, 64);

    __shared__ float wsum[4];
    if ((threadIdx.x & 63) == 0) wsum[wave] = ss;
    __syncthreads();
    const float total = wsum[sub * 2] + wsum[sub * 2 + 1];
    const float sc = 32.0f / fmaxf(sqrtf(total), 1e-12f);

    const float4 g0 = *(const float4*)(g + t * 8);
    const float4 g1 = *(const float4*)(g + t * 8 + 4);
    float4 o0, o1;
    o0.x = v[0] * sc * g0.x; o0.y = v[1] * sc * g0.y;
    o0.z = v[2] * sc * g0.z; o0.w = v[3] * sc * g0.w;
    o1.x = v[4] * sc * g1.x; o1.y = v[5] * sc * g1.y;
    o1.z = v[6] * sc * g1.z; o1.w = v[7] * sc * g1.w;
    *(float4*)(out + base)     = o0;
    *(float4*)(out + base + 4) = o1;
}

extern "C" void kernel_launch(void* const* d_in, const int* in_sizes, int n_in,
                              void* d_out, int out_size, void* d_ws, size_t ws_size,
                              hipStream_t stream) {
    const float* x     = (const float*)d_in[0];   // (16384, 1024)
    const float* w_qkv = (const float*)d_in[1];   // (1536, 1024)
    const float* w_out = (const float*)d_in[2];   // (1024, 512)
    const float* b_out = (const float*)d_in[3];   // (1024,)
    const float* g     = (const float*)d_in[4];   // (1, 1024)

    const int B = 16384, D = 1024, H = 512;
    const float* wv = w_qkv + (size_t)2 * H * D;  // v-rows: (512, 1024)

    char* ws = (char*)d_ws;
    size_t off = 0;
    __hip_bfloat16* weff_bf = (__hip_bfloat16*)(ws + off); off += (size_t)D * D * 2;  // 2 MB
    __hip_bfloat16* y_bf    = (__hip_bfloat16*)(ws + off); off += (size_t)B * D * 2;  // 33.6 MB
    __hip_bfloat16* x_bf    = (__hip_bfloat16*)(ws + off); off += (size_t)B * D * 2;  // 33.6 MB

    prep<<<256 + 2048, 256, 0, stream>>>(w_out, wv, weff_bf, x, x_bf);
    main_gemm<<<256, 512, 0, stream>>>(x_bf, weff_bf, b_out, y_bf);
    rmsnorm2<<<B / 2, 256, 0, stream>>>(y_bf, g, (float*)d_out);
}

// Round 8
// 175.299 us; speedup vs baseline: 1.0985x; 1.0110x over previous
//
#include <hip/hip_runtime.h>
#include <hip/hip_bf16.h>

// LinearAttention_MLP on MI355X — round 13: 2x4 wave geometry (LDS-traffic fix).
// Math: k-softmax over size-1 axis == 1 -> s = 0.125 exactly -> out = 0.125*v.
// Fold: y = x @ Weff^T, Weff = 0.125*Wo@Wv (1024x1024).
// Pipeline (3 launches):
//   prep       : [0..255] Weff = bf16(0.125*Wo@Wv); [256..2303] Xbf = bf16(X)
//   main_gemm  : y_bf = bf16(Xbf@Weff^T + b). 256x256, BK=64, 512 thr, dbuf
//                128KB. NEW: waves 2x4 (each 128 rows x 64 cols) instead of
//                1x8 (256x32). Per-wave LDS/tile: 36 -> 24 KB; per-CU LDS
//                2310 cyc < MFMA 2484 cyc -> MFMA-bound (was LDS-bound 3460).
//                Phases: P0 = rows wr*128..+63 (A quarters Q0/Q2) + all B;
//                        P1 = rows wr*128+64..+127 (Q1/Q3).
//                Staging (1 gll = one 64-row quarter; ledger-verified):
//                  P0: AQ1,AQ3(u+1) -> other buf (2 gll)
//                  P1: BQ0-3,AQ0,AQ2(u+2) -> read buf (6 gll) — all staged
//                      regions were read at P0, sealed by inter-phase barrier.
//                  boundary vmcnt(6) completes exactly tile u+1; u=14 vmcnt(0).
//   rmsnorm2   : out = y/max(||y||,eps)*g*32  (fp32, unchanged)
//
// Swizzle convention (validated, 0 bank conflicts):
//   STORE: LDS chunk c holds GLOBAL chunk c ^ (r&7)  (swizzle the global k only)
//   READ : global chunk q lives in LDS chunk q ^ (r&7)
//
// WORKSPACE: 2MB (Weff) + 33.6MB (y_bf) + 33.6MB (Xbf) = ~69.2 MB.

typedef __attribute__((ext_vector_type(8))) short bf16x8;
typedef __attribute__((ext_vector_type(4))) float f32x4;

struct alignas(16) bfvec8 { __hip_bfloat16 h[8]; };

__device__ __forceinline__ bfvec8 pack8(float4 a, float4 b) {
    bfvec8 o;
    o.h[0] = __float2bfloat16(a.x); o.h[1] = __float2bfloat16(a.y);
    o.h[2] = __float2bfloat16(a.z); o.h[3] = __float2bfloat16(a.w);
    o.h[4] = __float2bfloat16(b.x); o.h[5] = __float2bfloat16(b.y);
    o.h[6] = __float2bfloat16(b.z); o.h[7] = __float2bfloat16(b.w);
    return o;
}

// ---------------- prep: weff (blocks 0..255) + X->bf16 cvt (blocks 256..2303) ----------
__global__ __launch_bounds__(256)
void prep(const float* __restrict__ Wo, const float* __restrict__ Wv,
          __hip_bfloat16* __restrict__ Weff,
          const float* __restrict__ X, __hip_bfloat16* __restrict__ Xbf) {
    __shared__ __align__(16) __hip_bfloat16 As[64 * 32];
    __shared__ __align__(16) __hip_bfloat16 Bs[64 * 32];
    __shared__ __align__(16) float Bf[32 * 65];

    const int tid = threadIdx.x;

    if (blockIdx.x >= 256) {
        const size_t nv = (size_t)16384 * 1024 / 8;          // 2,097,152 vec8
        const size_t stride = (size_t)2048 * 256;
        for (size_t i = (size_t)(blockIdx.x - 256) * 256 + tid; i < nv; i += stride) {
            const float4 a = *(const float4*)(X + i * 8);
            const float4 b = *(const float4*)(X + i * 8 + 4);
            *(bfvec8*)(Xbf + i * 8) = pack8(a, b);
        }
        return;
    }

    // ---- weff body (validated): Weff = 0.125 * Wo @ Wv ----
    const int lane = tid & 63;
    const int wave = tid >> 6;
    const int wm   = wave >> 1;
    const int wn   = wave & 1;
    const int quad = lane >> 4;
    const int tr   = lane & 15;
    const int m0   = (blockIdx.x >> 4) * 64;
    const int n0   = (blockIdx.x & 15) * 64;

    f32x4 acc[2][2];
#pragma unroll
    for (int i = 0; i < 2; ++i)
#pragma unroll
        for (int j = 0; j < 2; ++j)
            acc[i][j] = (f32x4){0.f, 0.f, 0.f, 0.f};

    for (int kt = 0; kt < 512; kt += 32) {
        {
            int r = tid >> 2, c = tid & 3;
            int s = (r >> 1) & 3;
            int kg = (c ^ s) << 3;
            const float* sp = Wo + (size_t)(m0 + r) * 512 + kt + kg;
            float4 a = *(const float4*)sp, b = *(const float4*)(sp + 4);
            *(bfvec8*)(As + r * 32 + (c << 3)) = pack8(a, b);
        }
        {
            int kr = tid >> 3, c8 = (tid & 7) << 3;
            const float* sp = Wv + (size_t)(kt + kr) * 1024 + n0 + c8;
            float4 a = *(const float4*)sp, b = *(const float4*)(sp + 4);
            *(float4*)(Bf + kr * 65 + c8)     = a;
            *(float4*)(Bf + kr * 65 + c8 + 4) = b;
        }
        __syncthreads();
        {
            int n = tid >> 2, cc = tid & 3, k8 = cc << 3;
            float4 a, b;
            a.x = Bf[(k8 + 0) * 65 + n]; a.y = Bf[(k8 + 1) * 65 + n];
            a.z = Bf[(k8 + 2) * 65 + n]; a.w = Bf[(k8 + 3) * 65 + n];
            b.x = Bf[(k8 + 4) * 65 + n]; b.y = Bf[(k8 + 5) * 65 + n];
            b.z = Bf[(k8 + 6) * 65 + n]; b.w = Bf[(k8 + 7) * 65 + n];
            int cs = cc ^ ((n >> 1) & 3);
            *(bfvec8*)(Bs + n * 32 + cs * 8) = pack8(a, b);
        }
        __syncthreads();

        bf16x8 af[2], bfr[2];
#pragma unroll
        for (int mi = 0; mi < 2; ++mi) {
            int r = wm * 32 + mi * 16 + tr;
            int c = quad ^ ((r >> 1) & 3);
            af[mi] = *(const bf16x8*)(As + r * 32 + c * 8);
        }
#pragma unroll
        for (int ni = 0; ni < 2; ++ni) {
            int r = wn * 32 + ni * 16 + tr;
            int c = quad ^ ((r >> 1) & 3);
            bfr[ni] = *(const bf16x8*)(Bs + r * 32 + c * 8);
        }
#pragma unroll
        for (int mi = 0; mi < 2; ++mi)
#pragma unroll
            for (int ni = 0; ni < 2; ++ni)
                acc[mi][ni] = __builtin_amdgcn_mfma_f32_16x16x32_bf16(
                    af[mi], bfr[ni], acc[mi][ni], 0, 0, 0);
        __syncthreads();
    }

#pragma unroll
    for (int mi = 0; mi < 2; ++mi)
#pragma unroll
        for (int ni = 0; ni < 2; ++ni) {
            const int col = n0 + wn * 32 + ni * 16 + tr;
#pragma unroll
            for (int r = 0; r < 4; ++r) {
                const int row = m0 + wm * 32 + mi * 16 + quad * 4 + r;
                Weff[(size_t)row * 1024 + col] =
                    __float2bfloat16(acc[mi][ni][r] * 0.125f);
            }
        }
}

// ---------------- main GEMM: y = Xbf @ Weff^T + b, 256x256, 2x4 waves ----------------
// M=16384, N=1024, K=1024. Grid 256 blocks (64 m x 4 n), 512 threads (8 waves).
// LDS 128KB: buf b at b*32768 elems; A @ +0 (256x64), B @ +16384 (256x64).
// One gll = one 64-row quarter (512 thr x 16B = 8192B).

#define GLL(gp, lp) __builtin_amdgcn_global_load_lds( \
    (const __attribute__((address_space(1))) void*)(gp), \
    (__attribute__((address_space(3))) void*)(lp), 16, 0, 0)

#define STAGE_AQ(BUF, Q, U) \
    GLL(Xbf + Abase + (size_t)(Q) * 65536 + (size_t)(U) * 64, \
        sm + (BUF) * 32768 + (Q) * 4096 + tid * 8)

#define STAGE_BQ(BUF, Q, U) \
    GLL(Bt + Bbase + (size_t)(Q) * 65536 + (size_t)(U) * 64, \
        sm + (BUF) * 32768 + 16384 + (Q) * 4096 + tid * 8)

__global__ __launch_bounds__(512, 2)
void main_gemm(const __hip_bfloat16* __restrict__ Xbf,
               const __hip_bfloat16* __restrict__ Bt,
               const float* __restrict__ bias,
               __hip_bfloat16* __restrict__ Y) {
    __shared__ __align__(16) __hip_bfloat16 sm[2 * 32768];   // 128 KiB

    const int tid  = threadIdx.x;          // 0..511
    const int lane = tid & 63;
    const int w    = tid >> 6;             // wave 0..7
    const int wr   = w >> 2;               // wave row group (128 rows)
    const int wn   = w & 3;                // wave col group (64 cols)
    const int quad = lane >> 4;
    const int tr   = lane & 15;
    const int rlow = tr & 7;

    // XCD-aware: 256 blocks; XCD x gets orig chunk [x*32, x*32+32) (8 m x 4 n)
    const int xcd  = blockIdx.x & 7;
    const int orig = xcd * 32 + (blockIdx.x >> 3);
    const int m0   = (orig >> 2) * 256;
    const int n0   = (orig & 3) * 256;

    // Staging (linear LDS dest, inverse-swizzled global k). Thread covers
    // row-in-quarter tid>>3, chunk tid&7.
    const int sr = tid >> 3, scn = tid & 7;
    const int kg = ((scn ^ (sr & 7)) << 3);
    const size_t Abase = (size_t)(m0 + sr) * 1024 + kg;
    const size_t Bbase = (size_t)(n0 + sr) * 1024 + kg;

    // Read chunk offsets per ko: global chunk q = ko*4+quad lives in chunk q^rlow.
    int ac[2];
#pragma unroll
    for (int ko = 0; ko < 2; ++ko) ac[ko] = ((ko * 4 + quad) ^ rlow) * 8;
    const int rdA = tr * 64;                            // + quarter*4096 + mi*1024
    const int rdB = 16384 + wn * 4096 + tr * 64;        // + ni*1024

    f32x4 acc[8][4];
#pragma unroll
    for (int f = 0; f < 8; ++f)
#pragma unroll
        for (int ni = 0; ni < 4; ++ni)
            acc[f][ni] = (f32x4){0.f, 0.f, 0.f, 0.f};

    // ---- Prologue: tile 0 full (8 gll) + tile 1 early parts (6 gll) ----
    STAGE_AQ(0, 0, 0); STAGE_AQ(0, 1, 0); STAGE_AQ(0, 2, 0); STAGE_AQ(0, 3, 0);
    STAGE_BQ(0, 0, 0); STAGE_BQ(0, 1, 0); STAGE_BQ(0, 2, 0); STAGE_BQ(0, 3, 0);
    STAGE_BQ(1, 0, 1); STAGE_BQ(1, 1, 1); STAGE_BQ(1, 2, 1); STAGE_BQ(1, 3, 1);
    STAGE_AQ(1, 0, 1); STAGE_AQ(1, 2, 1);
    asm volatile("s_waitcnt vmcnt(6)" ::: "memory");     // tile 0 complete, 6 in flight
    __builtin_amdgcn_s_barrier();

    bf16x8 bfr[4][2];

    // ---- Main loop: 16 K-tiles x 2 phases ----
    for (int it = 0; it < 8; ++it) {
#pragma unroll
        for (int rb = 0; rb < 2; ++rb) {                 // rb = read buffer (static)
            const int u = it * 2 + rb;                   // K-tile index (uniform)

            // ======== P0: rows wr*128 .. +63 (quarter wr*2), all B ========
            bf16x8 af[4][2];
#pragma unroll
            for (int mi = 0; mi < 4; ++mi)
#pragma unroll
                for (int ko = 0; ko < 2; ++ko)
                    af[mi][ko] = *(const bf16x8*)(
                        sm + rb * 32768 + (wr * 2) * 4096 + mi * 1024 + rdA + ac[ko]);
#pragma unroll
            for (int ni = 0; ni < 4; ++ni)
#pragma unroll
                for (int ko = 0; ko < 2; ++ko)
                    bfr[ni][ko] = *(const bf16x8*)(
                        sm + rb * 32768 + rdB + ni * 1024 + ac[ko]);

            if (u + 1 < 16) { STAGE_AQ(rb ^ 1, 1, u + 1); STAGE_AQ(rb ^ 1, 3, u + 1); }

            __builtin_amdgcn_s_barrier();
            asm volatile("s_waitcnt lgkmcnt(0)" ::: "memory");
            __builtin_amdgcn_sched_barrier(0);

            __builtin_amdgcn_s_setprio(1);
#pragma unroll
            for (int mi = 0; mi < 4; ++mi)
#pragma unroll
                for (int ni = 0; ni < 4; ++ni)
#pragma unroll
                    for (int ko = 0; ko < 2; ++ko)
                        acc[mi][ni] = __builtin_amdgcn_mfma_f32_16x16x32_bf16(
                            af[mi][ko], bfr[ni][ko], acc[mi][ni], 0, 0, 0);
            __builtin_amdgcn_s_setprio(0);
            __builtin_amdgcn_s_barrier();

            // ======== P1: rows wr*128+64 .. +127 (quarter wr*2+1) ========
#pragma unroll
            for (int mi = 0; mi < 4; ++mi)
#pragma unroll
                for (int ko = 0; ko < 2; ++ko)
                    af[mi][ko] = *(const bf16x8*)(
                        sm + rb * 32768 + (wr * 2 + 1) * 4096 + mi * 1024 + rdA + ac[ko]);

            if (u + 2 < 16) {
                STAGE_BQ(rb, 0, u + 2); STAGE_BQ(rb, 1, u + 2);
                STAGE_BQ(rb, 2, u + 2); STAGE_BQ(rb, 3, u + 2);
                STAGE_AQ(rb, 0, u + 2); STAGE_AQ(rb, 2, u + 2);
            }

            __builtin_amdgcn_s_barrier();
            asm volatile("s_waitcnt lgkmcnt(0)" ::: "memory");
            __builtin_amdgcn_sched_barrier(0);

            __builtin_amdgcn_s_setprio(1);
#pragma unroll
            for (int mi = 0; mi < 4; ++mi)
#pragma unroll
                for (int ni = 0; ni < 4; ++ni)
#pragma unroll
                    for (int ko = 0; ko < 2; ++ko)
                        acc[4 + mi][ni] = __builtin_amdgcn_mfma_f32_16x16x32_bf16(
                            af[mi][ko], bfr[ni][ko], acc[4 + mi][ni], 0, 0, 0);
            __builtin_amdgcn_s_setprio(0);

            // boundary: counted drain completes exactly tile u+1
            if (u <= 13)      asm volatile("s_waitcnt vmcnt(6)" ::: "memory");
            else if (u == 14) asm volatile("s_waitcnt vmcnt(0)" ::: "memory");
            if (u < 15) __builtin_amdgcn_s_barrier();
        }
    }

    // ---- Epilogue: C/D layout col = lane&15 (tr), row = quad*4 + reg ----
    float bv[4]; int col[4];
#pragma unroll
    for (int ni = 0; ni < 4; ++ni) {
        col[ni] = n0 + wn * 64 + ni * 16 + tr;
        bv[ni]  = bias[col[ni]];
    }
#pragma unroll
    for (int f = 0; f < 8; ++f)
#pragma unroll
        for (int ni = 0; ni < 4; ++ni)
#pragma unroll
            for (int rr = 0; rr < 4; ++rr) {
                const int row = m0 + wr * 128 + (f >> 2) * 64 + (f & 3) * 16
                              + quad * 4 + rr;
                Y[(size_t)row * 1024 + col[ni]] =
                    __float2bfloat16(acc[f][ni][rr] + bv[ni]);
            }
}

// ---------------- norm: out = y / max(||y||,eps) * g * 32, 2 rows/block ----------------
__global__ __launch_bounds__(256)
void rmsnorm2(const __hip_bfloat16* __restrict__ y, const float* __restrict__ g,
              float* __restrict__ out) {
    const int wave = threadIdx.x >> 6;
    const int sub  = wave >> 1;
    const int t    = threadIdx.x & 127;
    const int row  = blockIdx.x * 2 + sub;
    const size_t base = (size_t)row * 1024 + t * 8;

    union { uint4 u; ushort s[8]; } U;
    U.u = *(const uint4*)(y + base);
    float v[8];
#pragma unroll
    for (int j = 0; j < 8; ++j)
        v[j] = __bfloat162float(*(const __hip_bfloat16*)&U.s[j]);

    float ss = 0.f;
#pragma unroll
    for (int j = 0; j < 8; ++j) ss += v[j] * v[j];
#pragma unroll
    for (int off = 32; off > 0; off >>= 1)
        ss += __shfl_down(ss, off, 64);

    __shared__ float wsum[4];
    if ((threadIdx.x & 63) == 0) wsum[wave] = ss;
    __syncthreads();
    const float total = wsum[sub * 2] + wsum[sub * 2 + 1];
    const float sc = 32.0f / fmaxf(sqrtf(total), 1e-12f);

    const float4 g0 = *(const float4*)(g + t * 8);
    const float4 g1 = *(const float4*)(g + t * 8 + 4);
    float4 o0, o1;
    o0.x = v[0] * sc * g0.x; o0.y = v[1] * sc * g0.y;
    o0.z = v[2] * sc * g0.z; o0.w = v[3] * sc * g0.w;
    o1.x = v[4] * sc * g1.x; o1.y = v[5] * sc * g1.y;
    o1.z = v[6] * sc * g1.z; o1.w = v[7] * sc * g1.w;
    *(float4*)(out + base)     = o0;
    *(float4*)(out + base + 4) = o1;
}

extern "C" void kernel_launch(void* const* d_in, const int* in_sizes, int n_in,
                              void* d_out, int out_size, void* d_ws, size_t ws_size,
                              hipStream_t stream) {
    const float* x     = (const float*)d_in[0];   // (16384, 1024)
    const float* w_qkv = (const float*)d_in[1];   // (1536, 1024)
    const float* w_out = (const float*)d_in[2];   // (1024, 512)
    const float* b_out = (const float*)d_in[3];   // (1024,)
    const float* g     = (const float*)d_in[4];   // (1, 1024)

    const int B = 16384, D = 1024, H = 512;
    const float* wv = w_qkv + (size_t)2 * H * D;  // v-rows: (512, 1024)

    char* ws = (char*)d_ws;
    size_t off = 0;
    __hip_bfloat16* weff_bf = (__hip_bfloat16*)(ws + off); off += (size_t)D * D * 2;  // 2 MB
    __hip_bfloat16* y_bf    = (__hip_bfloat16*)(ws + off); off += (size_t)B * D * 2;  // 33.6 MB
    __hip_bfloat16* x_bf    = (__hip_bfloat16*)(ws + off); off += (size_t)B * D * 2;  // 33.6 MB

    prep<<<256 + 2048, 256, 0, stream>>>(w_out, wv, weff_bf, x, x_bf);
    main_gemm<<<256, 512, 0, stream>>>(x_bf, weff_bf, b_out, y_bf);
    rmsnorm2<<<B / 2, 256, 0, stream>>>(y_bf, g, (float*)d_out);
}